// Round 10
// baseline (20.370 us; speedup 1.0000x reference)
//
#include <hip/hip_runtime.h>

// Problem geometry (f32):
//   x:   [8, 16, 3, 224, 224]
//   out: [8, 16, 224, 224, 3]  (permute 0,1,4,3,2)
// batch 0: y[0]=x[0]; y[t] = x[t] - 0.4*y[t-1] + 3   (elementwise c,h,w)
// batches 1..6: zeros
// batch 7: z[0]=0; z[t] = 3 - 0.4*z[t-1], broadcast over (w,h,c)
//
// Round 10: offload the 57.8-MB zero region (batches 1..6, contiguous) to
// hipMemsetAsync — the rocclr fill path demonstrably sustains 6.8 TB/s (85%
// of peak) vs our mixed kernel's 5.0 TB/s. Kernel now handles only batch 0
// (r6's proven LDS-tile path, unchanged: 196 tiles at bid%9, one barrier
// pair per 4-t phase, all 48 loads up front) + batch-7 broadcast fill.
// memset + kernel serialize on the stream: ~8.5 + ~5 us predicted.

typedef float fx4 __attribute__((ext_vector_type(4)));

#define SP        150528    // 3*224*224 elements per (b,t) slice
#define TT        16
#define CH_STRIDE 50176     // 224*224
#define BSTRIDE   2408448   // 16*SP elements per batch

#define NWT    7            // w tiles (224/32)
#define NTILES 196          // 28 h-tiles x 7 w-tiles
#define SPREAD 9            // coprime to 8 -> uniform over XCDs

#define B7FILL4 602112      // 16*SP/4 vec4s (batch 7 only)
#define TSLICE4 37632       // SP/4
#define NBLOCKS 2048
#define NFILL   (NBLOCKS - NTILES)   // 1852
#define RFILL   326                  // ceil(B7FILL4/NFILL)

__global__ __launch_bounds__(256) void temporal_fused(
    const float* __restrict__ x, float* __restrict__ out)
{
    const int tid = threadIdx.x;
    const int bid = blockIdx.x;

    // 12 KiB: 4 t-slices of [32 w][6 slots][4 floats]
    __shared__ float lds[4 * 768];

    const bool is_tile = (bid % SPREAD == 0) && (bid / SPREAD) < NTILES;

    if (is_tile) {
        // ------------- batch-0 recurrence, tile = 8h x 32w, 3c/thread -----
        const int tileid = bid / SPREAD;
        const int h0 = (tileid / NWT) * 8;
        const int w0 = (tileid % NWT) * 32;
        const int dw = tid & 31;       // w offset 0..31
        const int hh = tid >> 5;       // h offset 0..7
        const int rbase = (h0 + hh) * 224 + w0 + dw;

        // all 48 loads independent, before any barrier -> one HBM latency
        float v[TT][3];
        #pragma unroll
        for (int t = 0; t < TT; ++t) {
            #pragma unroll
            for (int c = 0; c < 3; ++c)
                v[t][c] = x[t * SP + c * CH_STRIDE + rbase];
        }

        // LDS write bases: logical idx = hh*3+c in [0,24); slot s=idx>>2,
        // phys slot = (s+dw)%6 (rotate swizzle; verified absmax=0 r5/r6)
        int wbase[3];
        #pragma unroll
        for (int c = 0; c < 3; ++c) {
            const int idx = hh * 3 + c;
            const int s = idx >> 2, o = idx & 3;
            wbase[c] = dw * 24 + ((s + dw) % 6) * 4 + o;
        }

        const int ob0 = w0 * 672 + h0 * 3;
        float y0 = 0.f, y1 = 0.f, y2 = 0.f;

        #pragma unroll
        for (int p = 0; p < 4; ++p) {
            // compute 4 t-slices into LDS
            #pragma unroll
            for (int tl = 0; tl < 4; ++tl) {
                const int t = p * 4 + tl;
                if (t == 0) { y0 = v[0][0]; y1 = v[0][1]; y2 = v[0][2]; }
                else {
                    y0 = v[t][0] - 0.4f * y0 + 3.0f;
                    y1 = v[t][1] - 0.4f * y1 + 3.0f;
                    y2 = v[t][2] - 0.4f * y2 + 3.0f;
                }
                lds[tl * 768 + wbase[0]] = y0;
                lds[tl * 768 + wbase[1]] = y1;
                lds[tl * 768 + wbase[2]] = y2;
            }
            __syncthreads();

            // readout: 4t x 32w x 6 vec4 = 768 vec4s = 3 iters x 256 thr
            const fx4* lds4 = reinterpret_cast<const fx4*>(lds);
            #pragma unroll
            for (int k = 0; k < 3; ++k) {
                const int j = tid + k * 256;       // < 768
                const int tl = j / 192;
                const int r = j - tl * 192;
                const int w = r / 6;
                const int piece = r - w * 6;
                const int phys = (piece + w) % 6;
                const fx4 f4 = lds4[(tl * 768 + w * 24 + phys * 4) >> 2];
                *reinterpret_cast<fx4*>(
                    out + (p * 4 + tl) * SP + ob0 + w * 672 + piece * 4) = f4;
            }
            __syncthreads();   // protect LDS before next phase overwrites
        }
        return;
    }

    // ---------------- fill: batch 7 broadcast z[t] only ------------------
    const int tiles_before = min((bid + SPREAD - 1) / SPREAD, NTILES);
    const int fidx = bid - tiles_before;          // 0..NFILL-1

    fx4* out4 = reinterpret_cast<fx4*>(out + 7 * BSTRIDE); // batch-7 start
    int q   = fidx * RFILL;
    int end = q + RFILL;
    if (end > B7FILL4) end = B7FILL4;

    while (q < end) {
        const int t = q / TSLICE4;                // 0..15
        int send = (t + 1) * TSLICE4;
        if (send > end) send = end;
        float z = 0.0f;
        for (int i = 0; i < t; ++i) z = 3.0f - 0.4f * z;
        fx4 val;
        val.x = z; val.y = z; val.z = z; val.w = z;
        for (int i = q + tid; i < send; i += 256)
            out4[i] = val;
        q = send;
    }
}

extern "C" void kernel_launch(void* const* d_in, const int* in_sizes, int n_in,
                              void* d_out, int out_size, void* d_ws, size_t ws_size,
                              hipStream_t stream) {
    const float* x = (const float*)d_in[0];
    float* out = (float*)d_out;
    // batches 1..6 are zeros: one contiguous 57.8-MB region -> DMA-path
    // memset (graph-capture-legal; becomes a memset node) at ~85% peak BW.
    hipMemsetAsync(out + BSTRIDE, 0, (size_t)6 * BSTRIDE * sizeof(float), stream);
    temporal_fused<<<NBLOCKS, 256, 0, stream>>>(x, out);
}

// Round 11
// 17.291 us; speedup vs baseline: 1.1781x; 1.1781x over previous
//
#include <hip/hip_runtime.h>

// Problem geometry (f32):
//   x:   [8, 16, 3, 224, 224]
//   out: [8, 16, 224, 224, 3]  (permute 0,1,4,3,2)
// batch 0: y[0]=x[0]; y[t] = x[t] - 0.4*y[t-1] + 3   (elementwise c,h,w)
// batches 1..6: zeros
// batch 7: z[0]=0; z[t] = 3 - 0.4*z[t-1], broadcast over (w,h,c)
//
// FINAL (= round 6, best of 10 rounds @ 17.3 us): spacing-9 tile placement
// (coprime to 8 XCDs -> uniform heavy-block distribution; the single biggest
// lever, r2->r3 24.4->17.8), all 48 recurrence loads issued before any
// barrier (one HBM latency; r7 showed per-phase prefetch re-serializes via
// vmcnt(0) at __syncthreads), 4-phase 12-KiB LDS staging -> aligned vec4
// stores, plain (non-NT) stores everywhere (r5: NT regresses), single fused
// kernel (r10: hipMemsetAsync fill path runs at only 1.2 TB/s for 58 MB).
// Floor model: 87 MB compulsory @ ~6.1 TB/s mixed-stream + ~2 us overhead
// = 16.5-17.5 us; disproven alternatives: store granularity (r3~r6),
// line-exact writes (r8), CU balance (r9), memset split (r10).

typedef float fx4 __attribute__((ext_vector_type(4)));

#define SP        150528    // 3*224*224 elements per (b,t) slice
#define TT        16
#define CH_STRIDE 50176     // 224*224
#define BSTRIDE   2408448   // 16*SP elements per batch

#define NWT    7            // w tiles (224/32)
#define NTILES 196          // 28 h-tiles x 7 w-tiles

#define FILL4   4214784     // 7 * 16*SP/4 vec4s (batches 1..7)
#define TSLICE4 37632       // SP/4
#define NBLOCKS 2048
#define NFILL   (NBLOCKS - NTILES)   // 1852
#define RFILL   2276                 // ceil(FILL4/NFILL)
#define SPREAD  9                    // coprime to 8 -> uniform over XCDs

__global__ __launch_bounds__(256) void temporal_fused(
    const float* __restrict__ x, float* __restrict__ out)
{
    const int tid = threadIdx.x;
    const int bid = blockIdx.x;

    // 12 KiB: 4 t-slices of [32 w][6 slots][4 floats]
    __shared__ float lds[4 * 768];

    const bool is_tile = (bid % SPREAD == 0) && (bid / SPREAD) < NTILES;

    if (is_tile) {
        // ------------- batch-0 recurrence, tile = 8h x 32w, 3c/thread -----
        const int tileid = bid / SPREAD;
        const int h0 = (tileid / NWT) * 8;
        const int w0 = (tileid % NWT) * 32;
        const int dw = tid & 31;       // w offset 0..31
        const int hh = tid >> 5;       // h offset 0..7
        const int rbase = (h0 + hh) * 224 + w0 + dw;

        // all 48 loads independent, before any barrier -> one HBM latency
        float v[TT][3];
        #pragma unroll
        for (int t = 0; t < TT; ++t) {
            #pragma unroll
            for (int c = 0; c < 3; ++c)
                v[t][c] = x[t * SP + c * CH_STRIDE + rbase];
        }

        // LDS write bases: logical idx = hh*3+c in [0,24); slot s=idx>>2,
        // phys slot = (s+dw)%6 (rotate swizzle, alignment-preserving;
        // verified absmax=0 across r5/r6/r10)
        int wbase[3];
        #pragma unroll
        for (int c = 0; c < 3; ++c) {
            const int idx = hh * 3 + c;
            const int s = idx >> 2, o = idx & 3;
            wbase[c] = dw * 24 + ((s + dw) % 6) * 4 + o;
        }

        const int ob0 = w0 * 672 + h0 * 3;
        float y0 = 0.f, y1 = 0.f, y2 = 0.f;

        #pragma unroll
        for (int p = 0; p < 4; ++p) {
            // compute 4 t-slices into LDS
            #pragma unroll
            for (int tl = 0; tl < 4; ++tl) {
                const int t = p * 4 + tl;
                if (t == 0) { y0 = v[0][0]; y1 = v[0][1]; y2 = v[0][2]; }
                else {
                    y0 = v[t][0] - 0.4f * y0 + 3.0f;
                    y1 = v[t][1] - 0.4f * y1 + 3.0f;
                    y2 = v[t][2] - 0.4f * y2 + 3.0f;
                }
                lds[tl * 768 + wbase[0]] = y0;
                lds[tl * 768 + wbase[1]] = y1;
                lds[tl * 768 + wbase[2]] = y2;
            }
            __syncthreads();

            // readout: 4t x 32w x 6 vec4 = 768 vec4s = 3 iters x 256 thr
            const fx4* lds4 = reinterpret_cast<const fx4*>(lds);
            #pragma unroll
            for (int k = 0; k < 3; ++k) {
                const int j = tid + k * 256;       // < 768
                const int tl = j / 192;
                const int r = j - tl * 192;
                const int w = r / 6;
                const int piece = r - w * 6;
                const int phys = (piece + w) % 6;
                const fx4 f4 = lds4[(tl * 768 + w * 24 + phys * 4) >> 2];
                *reinterpret_cast<fx4*>(
                    out + (p * 4 + tl) * SP + ob0 + w * 672 + piece * 4) = f4;
            }
            __syncthreads();   // protect LDS before next phase overwrites
        }
        return;
    }

    // ---------------- fill: batches 1..6 zeros, batch 7 broadcast z[t] ----
    const int tiles_before = min((bid + SPREAD - 1) / SPREAD, NTILES);
    const int fidx = bid - tiles_before;          // 0..NFILL-1

    fx4* out4 = reinterpret_cast<fx4*>(out + BSTRIDE); // batch-1 start
    int q   = fidx * RFILL;
    int end = q + RFILL;
    if (end > FILL4) end = FILL4;

    while (q < end) {
        const int slice = q / TSLICE4;            // 0..111 = (batch-1)*16 + t
        int send = (slice + 1) * TSLICE4;
        if (send > end) send = end;
        float zv = 0.0f;
        if ((slice >> 4) == 6) {                  // batch 7
            const int t = slice & 15;
            float z = 0.0f;
            for (int i = 0; i < t; ++i) z = 3.0f - 0.4f * z;
            zv = z;
        }
        fx4 val;
        val.x = zv; val.y = zv; val.z = zv; val.w = zv;
        for (int i = q + tid; i < send; i += 256)
            out4[i] = val;
        q = send;
    }
}

extern "C" void kernel_launch(void* const* d_in, const int* in_sizes, int n_in,
                              void* d_out, int out_size, void* d_ws, size_t ws_size,
                              hipStream_t stream) {
    const float* x = (const float*)d_in[0];
    float* out = (float*)d_out;
    temporal_fused<<<NBLOCKS, 256, 0, stream>>>(x, out);
}